// Round 7
// baseline (82.108 us; speedup 1.0000x reference)
//
#include <hip/hip_runtime.h>
#include <hip/hip_bf16.h>

#define DD 64      // feature dim K
#define TN 64      // rows per block (X1)
#define TM 128     // cols per sub-tile (X2); each block does 2 column-adjacent sub-tiles

typedef short short8 __attribute__((ext_vector_type(8)));
typedef unsigned short us8 __attribute__((ext_vector_type(8)));
typedef float f32x4 __attribute__((ext_vector_type(4)));

__device__ __forceinline__ float bf2f(unsigned short h) {
    union { unsigned u; float f; } v; v.u = ((unsigned)h) << 16;
    return v.f;
}
__device__ __forceinline__ unsigned short f2bf(float x) {
    __hip_bfloat16 b = __float2bfloat16(x);
    unsigned short u;
    __builtin_memcpy(&u, &b, 2);
    return u;
}

__global__ __launch_bounds__(256, 2) void sqexp_kernel(
    const float* __restrict__ X1, const float* __restrict__ X2,
    const float* __restrict__ lp, const float* __restrict__ sfp,
    float* __restrict__ out, int N, int M)
{
    // Disjoint regions — NO aliasing: B tiles (hi|lo, 32KB) + out-stage (32KB).
    __shared__ __align__(16) unsigned char Bbuf[2 * TM * DD * 2];
    __shared__ __align__(16) unsigned char Obuf[TN * TM * 4];
    __shared__ float sq1[TN];
    __shared__ float sq2[TM];

    unsigned short* Bh = (unsigned short*)Bbuf;
    unsigned short* Bl = (unsigned short*)(Bbuf + TM * DD * 2);

    const int t    = threadIdx.x;
    const int w    = t >> 6;
    const int lane = t & 63;
    const int n0   = blockIdx.y * TN;
    const int m0   = blockIdx.x * (2 * TM);

    const int wr = (w >> 1) * 32;    // 2x2 wave grid: 32 rows x 64 cols each
    const int wc = (w & 1) * 64;

    const float lv_ = lp[0], sf = sfp[0];
    const float c1  = -0.5f / (lv_ * lv_);
    const float cm2 = -2.0f * c1;
    const float amp = sf * sf;

    const int brow_ = t >> 1;        // B staging: 2 threads per X2 row
    const int bhalf = t & 1;

    // ---- helpers ----
    auto loadB = [&](int mbase, float4 (&f)[8]) {
        const float4* Bp = (const float4*)(X2 + (size_t)(mbase + brow_) * DD) + bhalf * 8;
        #pragma unroll
        for (int j = 0; j < 8; ++j) f[j] = Bp[j];
    };
    auto writeB = [&](float4 (&f)[8]) {
        float s2 = 0.0f;
        #pragma unroll
        for (int c = 0; c < 4; ++c) {
            float4 f0 = f[2 * c], f1 = f[2 * c + 1];
            float xs[8] = { f0.x, f0.y, f0.z, f0.w, f1.x, f1.y, f1.z, f1.w };
            us8 hv, lv;
            #pragma unroll
            for (int e = 0; e < 8; ++e) {
                s2 = fmaf(xs[e], xs[e], s2);
                unsigned short h = f2bf(xs[e]);
                hv[e] = h;
                lv[e] = f2bf(xs[e] - bf2f(h));
            }
            int byte = brow_ * 128 + (((bhalf * 4 + c) * 16) ^ ((brow_ & 7) << 4));
            *(us8*)&Bh[byte >> 1] = hv;
            *(us8*)&Bl[byte >> 1] = lv;
        }
        s2 += __shfl_xor(s2, 1);
        if (bhalf == 0) sq2[brow_] = s2;
    };

    short8 ah[2][2], al[2][2];       // [fm][ks]
    auto computeTile = [&](f32x4 (&acc)[2][4]) {
        #pragma unroll
        for (int ks = 0; ks < 2; ++ks) {
            #pragma unroll
            for (int fn = 0; fn < 4; ++fn) {
                int br   = wc + fn * 16 + (lane & 15);
                int byte = br * 128 + (((ks * 64) + (lane >> 4) * 16) ^ ((br & 7) << 4));
                short8 bh = *(const short8*)&Bh[byte >> 1];
                short8 bl = *(const short8*)&Bl[byte >> 1];
                #pragma unroll
                for (int fm = 0; fm < 2; ++fm) {
                    acc[fm][fn] = __builtin_amdgcn_mfma_f32_16x16x32_bf16(bh, ah[fm][ks], acc[fm][fn], 0, 0, 0);
                    acc[fm][fn] = __builtin_amdgcn_mfma_f32_16x16x32_bf16(bl, ah[fm][ks], acc[fm][fn], 0, 0, 0);
                    acc[fm][fn] = __builtin_amdgcn_mfma_f32_16x16x32_bf16(bh, al[fm][ks], acc[fm][fn], 0, 0, 0);
                }
            }
        }
    };
    auto epilogueTile = [&](f32x4 (&acc)[2][4]) {
        float a1[2];
        #pragma unroll
        for (int fm = 0; fm < 2; ++fm) a1[fm] = c1 * sq1[wr + fm * 16 + (lane & 15)];
        #pragma unroll
        for (int fn = 0; fn < 4; ++fn) {
            f32x4 s  = *(const f32x4*)&sq2[wc + fn * 16 + (lane >> 4) * 4];
            f32x4 a2 = c1 * s;
            #pragma unroll
            for (int fm = 0; fm < 2; ++fm) {
                f32x4 o;
                #pragma unroll
                for (int r = 0; r < 4; ++r) {
                    float arg = fminf(fmaf(cm2, acc[fm][fn][r], a1[fm] + a2[r]), 0.0f);
                    o[r] = amp * __expf(arg);
                }
                int R = wr + fm * 16 + (lane & 15);
                int C = wc + fn * 16 + (lane >> 4) * 4;
                *(f32x4*)(Obuf + R * 512 + ((C * 4) ^ ((R & 7) << 4))) = o;
            }
        }
    };
    auto storeTile = [&](int mbase) {
        #pragma unroll
        for (int i = 0; i < 8; ++i) {
            int R = w * 16 + i * 2 + (lane >> 5);
            int c = lane & 31;
            f32x4 v = *(const f32x4*)(Obuf + R * 512 + ((c ^ (R & 7)) * 16));
            *(f32x4*)&out[(size_t)(n0 + R) * M + mbase + 4 * c] = v;
        }
    };

    // ---- stage A fragments (shared by both sub-tiles) + sq1 ----
    #pragma unroll
    for (int fm = 0; fm < 2; ++fm) {
        const int row = n0 + wr + fm * 16 + (lane & 15);
        const float4* Ap = (const float4*)(X1 + (size_t)row * DD) + (lane >> 4) * 2;
        float p = 0.0f;
        #pragma unroll
        for (int ks = 0; ks < 2; ++ks) {
            float4 f0 = Ap[ks * 8];
            float4 f1 = Ap[ks * 8 + 1];
            float xs[8] = { f0.x, f0.y, f0.z, f0.w, f1.x, f1.y, f1.z, f1.w };
            us8 hv, lv;
            #pragma unroll
            for (int e = 0; e < 8; ++e) {
                p = fmaf(xs[e], xs[e], p);
                unsigned short h = f2bf(xs[e]);
                hv[e] = h;
                lv[e] = f2bf(xs[e] - bf2f(h));
            }
            __builtin_memcpy(&ah[fm][ks], &hv, 16);
            __builtin_memcpy(&al[fm][ks], &lv, 16);
        }
        p += __shfl_xor(p, 16);
        p += __shfl_xor(p, 32);
        if ((w & 1) == 0 && (lane >> 4) == 0) sq1[wr + fm * 16 + lane] = p;
    }

    // ---- tile 0: stage B0, compute, epilogue ----
    {
        float4 f[8];
        loadB(m0, f);
        writeB(f);
    }
    __syncthreads();                 // b1: B0 + sq in LDS

    f32x4 accA[2][4] = {};
    computeTile(accA);
    epilogueTile(accA);              // writes Obuf (fresh region; no barrier needed)
    __syncthreads();                 // b2: Obuf complete; B0 reads complete

    // ---- pipeline: issue B1 loads -> tile0 stores (fire & forget) -> B1 LDS ----
    {
        float4 f[8];
        loadB(m0 + TM, f);           // global loads issued first (latency hides below)
        storeTile(m0);               // tile0 store-issue overlaps B1 load latency;
                                     // drain overlaps tile1 compute below
        writeB(f);
    }
    __syncthreads();                 // b3: B1 in LDS; Obuf reads complete

    f32x4 accB[2][4] = {};
    computeTile(accB);               // store-drain of tile0 hides under this
    epilogueTile(accB);
    __syncthreads();                 // b4: Obuf complete

    storeTile(m0 + TM);
}

extern "C" void kernel_launch(void* const* d_in, const int* in_sizes, int n_in,
                              void* d_out, int out_size, void* d_ws, size_t ws_size,
                              hipStream_t stream) {
    const float* X1 = (const float*)d_in[0];
    const float* X2 = (const float*)d_in[1];
    const float* lp = (const float*)d_in[2];
    const float* sf = (const float*)d_in[3];
    float* out = (float*)d_out;
    const int N = in_sizes[0] / DD;
    const int M = in_sizes[1] / DD;
    dim3 grid(M / (2 * TM), N / TN);   // 32 x 128 = 4096 blocks
    sqexp_kernel<<<grid, 256, 0, stream>>>(X1, X2, lp, sf, out, N, M);
}

// Round 8
// 78.116 us; speedup vs baseline: 1.0511x; 1.0511x over previous
//
#include <hip/hip_runtime.h>
#include <hip/hip_bf16.h>

#define DD 64      // feature dim K
#define TN 128     // output rows per block  (X1 rows)
#define TM 256     // output cols per block  (X2 rows)

typedef short short8 __attribute__((ext_vector_type(8)));
typedef unsigned short us8 __attribute__((ext_vector_type(8)));
typedef float f32x4 __attribute__((ext_vector_type(4)));

__device__ __forceinline__ float bf2f(unsigned short h) {
    union { unsigned u; float f; } v; v.u = ((unsigned)h) << 16;
    return v.f;
}
__device__ __forceinline__ unsigned short f2bf(float x) {
    __hip_bfloat16 b = __float2bfloat16(x);
    unsigned short u;
    __builtin_memcpy(&u, &b, 2);
    return u;
}

__global__ __launch_bounds__(256, 2) void sqexp_kernel(
    const float* __restrict__ X1, const float* __restrict__ X2,
    const float* __restrict__ lp, const float* __restrict__ sfp,
    float* __restrict__ out, int N, int M)
{
    // B hi/lo bf16 tiles (2 x 32KB) during MFMA; SAME 64KB aliased as the f32
    // out-staging tile (64 rows x 1KB) during the two store phases.
    __shared__ __align__(16) unsigned char ldsbuf[TM * DD * 2 * 2];
    __shared__ float sq1[TN];
    __shared__ float sq2[TM];

    unsigned short* Bh = (unsigned short*)ldsbuf;
    unsigned short* Bl = (unsigned short*)(ldsbuf + TM * DD * 2);

    const int t    = threadIdx.x;
    const int w    = t >> 6;
    const int lane = t & 63;
    const int n0   = blockIdx.y * TN;
    const int m0   = blockIdx.x * TM;

    const int wr = (w >> 1) * 64;    // 2x2 wave grid: each wave 64 rows x 128 cols
    const int wc = (w & 1) * 128;

    // ---- B staging: one X2 row per thread -> hi/lo bf16 LDS (swizzled) + sq2 ----
    {
        const float4* Bp = (const float4*)(X2 + (size_t)(m0 + t) * DD);
        float4 bv[16];
        #pragma unroll
        for (int j = 0; j < 16; ++j) bv[j] = Bp[j];

        float s2 = 0.0f;
        #pragma unroll
        for (int c = 0; c < 8; ++c) {
            float4 f0 = bv[2 * c], f1 = bv[2 * c + 1];
            float xs[8] = { f0.x, f0.y, f0.z, f0.w, f1.x, f1.y, f1.z, f1.w };
            us8 hv, lv;
            #pragma unroll
            for (int e = 0; e < 8; ++e) {
                s2 = fmaf(xs[e], xs[e], s2);
                unsigned short h = f2bf(xs[e]);
                hv[e] = h;
                lv[e] = f2bf(xs[e] - bf2f(h));
            }
            int byte = t * 128 + ((c * 16) ^ ((t & 7) << 4));
            *(us8*)&Bh[byte >> 1] = hv;
            *(us8*)&Bl[byte >> 1] = lv;
        }
        sq2[t] = s2;
    }

    // ---- A fragments straight into registers (rows L2/L3-resident) + sq1 ----
    short8 ah[4][2], al[4][2];       // [fm][ks]
    #pragma unroll
    for (int fm = 0; fm < 4; ++fm) {
        const int row = n0 + wr + fm * 16 + (lane & 15);
        const float4* Ap = (const float4*)(X1 + (size_t)row * DD) + (lane >> 4) * 2;
        float p = 0.0f;
        #pragma unroll
        for (int ks = 0; ks < 2; ++ks) {
            float4 f0 = Ap[ks * 8];
            float4 f1 = Ap[ks * 8 + 1];
            float xs[8] = { f0.x, f0.y, f0.z, f0.w, f1.x, f1.y, f1.z, f1.w };
            us8 hv, lv;
            #pragma unroll
            for (int e = 0; e < 8; ++e) {
                p = fmaf(xs[e], xs[e], p);
                unsigned short h = f2bf(xs[e]);
                hv[e] = h;
                lv[e] = f2bf(xs[e] - bf2f(h));
            }
            __builtin_memcpy(&ah[fm][ks], &hv, 16);
            __builtin_memcpy(&al[fm][ks], &lv, 16);
        }
        p += __shfl_xor(p, 16);
        p += __shfl_xor(p, 32);
        if ((w & 1) == 0 && (lane >> 4) == 0) sq1[wr + fm * 16 + lane] = p;
    }
    __syncthreads();                 // b1: B tile + sq in LDS

    // ---- MFMA: cross = hiA*hiB + hiA*loB + loA*hiB (operands swapped so the
    //      C/D reg index walks the M/contiguous dim) ----
    f32x4 acc[4][8] = {};
    #pragma unroll
    for (int ks = 0; ks < 2; ++ks) {
        #pragma unroll
        for (int fn = 0; fn < 8; ++fn) {
            int brow = wc + fn * 16 + (lane & 15);
            int byte = brow * 128 + (((ks * 64) + (lane >> 4) * 16) ^ ((brow & 7) << 4));
            short8 bh = *(const short8*)&Bh[byte >> 1];
            short8 bl = *(const short8*)&Bl[byte >> 1];
            #pragma unroll
            for (int fm = 0; fm < 4; ++fm) {
                acc[fm][fn] = __builtin_amdgcn_mfma_f32_16x16x32_bf16(bh, ah[fm][ks], acc[fm][fn], 0, 0, 0);
                acc[fm][fn] = __builtin_amdgcn_mfma_f32_16x16x32_bf16(bl, ah[fm][ks], acc[fm][fn], 0, 0, 0);
                acc[fm][fn] = __builtin_amdgcn_mfma_f32_16x16x32_bf16(bh, al[fm][ks], acc[fm][fn], 0, 0, 0);
            }
        }
    }
    __syncthreads();                 // b2: all B-LDS reads done -> alias as Obuf

    const float lv_ = lp[0], sf = sfp[0];
    const float c1  = -0.5f / (lv_ * lv_);
    const float cm2 = -2.0f * c1;
    const float amp = sf * sf;

    float a1[4];
    #pragma unroll
    for (int fm = 0; fm < 4; ++fm) a1[fm] = c1 * sq1[wr + fm * 16 + (lane & 15)];

    // ---- two store phases: phase p covers block rows [64p, 64p+64) ----
    #pragma unroll
    for (int p = 0; p < 2; ++p) {
        // epilogue into Obuf: only the waves owning these rows (wr == 64p)
        if ((w >> 1) == p) {
            #pragma unroll
            for (int fn = 0; fn < 8; ++fn) {
                f32x4 s  = *(const f32x4*)&sq2[wc + fn * 16 + (lane >> 4) * 4];
                f32x4 a2 = c1 * s;
                #pragma unroll
                for (int fm = 0; fm < 4; ++fm) {
                    f32x4 o;
                    #pragma unroll
                    for (int r = 0; r < 4; ++r) {
                        float arg = fminf(fmaf(cm2, acc[fm][fn][r], a1[fm] + a2[r]), 0.0f);
                        o[r] = amp * __expf(arg);
                    }
                    int R = fm * 16 + (lane & 15);               // phase-local row 0..63
                    int C = wc + fn * 16 + (lane >> 4) * 4;
                    *(f32x4*)(ldsbuf + R * 1024 + ((C * 4) ^ ((R & 7) << 4))) = o;
                }
            }
        }
        __syncthreads();             // Obuf(phase p) complete

        // streaming store: all 4 waves, one wave instr = one contiguous 1KB row
        #pragma unroll
        for (int i = 0; i < 16; ++i) {
            int R = w * 16 + i;      // phase-local row
            f32x4 v = *(const f32x4*)(ldsbuf + R * 1024 + ((lane ^ (R & 7)) * 16));
            size_t off = (size_t)(n0 + p * 64 + R) * M + m0 + 4 * lane;
            *(f32x4*)&out[off] = v;
        }
        __syncthreads();             // Obuf reads done before next phase overwrites
    }
}

extern "C" void kernel_launch(void* const* d_in, const int* in_sizes, int n_in,
                              void* d_out, int out_size, void* d_ws, size_t ws_size,
                              hipStream_t stream) {
    const float* X1 = (const float*)d_in[0];
    const float* X2 = (const float*)d_in[1];
    const float* lp = (const float*)d_in[2];
    const float* sf = (const float*)d_in[3];
    float* out = (float*)d_out;
    const int N = in_sizes[0] / DD;
    const int M = in_sizes[1] / DD;
    dim3 grid(M / TM, N / TN);   // 32 x 64 = 2048 blocks
    sqexp_kernel<<<grid, 256, 0, stream>>>(X1, X2, lp, sf, out, N, M);
}